// Round 5
// baseline (157.176 us; speedup 1.0000x reference)
//
#include <hip/hip_runtime.h>
#include <cstdint>

#define LL 2048
#define HH 16
#define DD 64
#define LSTR 1024      // H*D
#define EPSF 1e-6f
#define PAD 72         // ushorts per LDS row: 144 B = 16B-aligned
// swizzle for transposed-store tiles accessed with b128 frags
#define SWZ(row, off) ((row)*PAD + ((off) ^ ((((row)>>3)&7)<<3)))

typedef __bf16 bf16x8 __attribute__((ext_vector_type(8)));
typedef float floatx4 __attribute__((ext_vector_type(4)));
typedef unsigned short ushortx8 __attribute__((ext_vector_type(8)));
typedef unsigned short ushortx4 __attribute__((ext_vector_type(4)));
typedef unsigned short ushortx2 __attribute__((ext_vector_type(2)));

static __device__ __forceinline__ float fmap(float x){ return x > 0.f ? x + 1.f : __expf(x); }
static __device__ __forceinline__ unsigned short f2bf(float f){
    return __builtin_bit_cast(unsigned short, static_cast<__bf16>(f));   // RNE, 1 VALU op
}
static __device__ __forceinline__ float bf2f(unsigned short s){
    unsigned u = ((unsigned)s) << 16;
    return __builtin_bit_cast(float, u);
}
static __device__ __forceinline__ bf16x8 ldf(const unsigned short* p){
    return __builtin_bit_cast(bf16x8, *(const ushortx8*)p);
}

// store rows r, r+1 of an [s][d]-layout tile (bf16), optional feature map (unswizzled)
template<bool MAP>
static __device__ __forceinline__ void st_sd(unsigned short* base, int r, int c, float4 a, float4 b){
    if (MAP) {
        *(ushortx4*)(base + r*PAD + c)     = ushortx4{ f2bf(fmap(a.x)), f2bf(fmap(a.y)), f2bf(fmap(a.z)), f2bf(fmap(a.w)) };
        *(ushortx4*)(base + (r+1)*PAD + c) = ushortx4{ f2bf(fmap(b.x)), f2bf(fmap(b.y)), f2bf(fmap(b.z)), f2bf(fmap(b.w)) };
    } else {
        *(ushortx4*)(base + r*PAD + c)     = ushortx4{ f2bf(a.x), f2bf(a.y), f2bf(a.z), f2bf(a.w) };
        *(ushortx4*)(base + (r+1)*PAD + c) = ushortx4{ f2bf(b.x), f2bf(b.y), f2bf(b.z), f2bf(b.w) };
    }
}
// transposed store into a [d][s]- or [m][s]-layout tile (bf16), SWZ-swizzled
template<bool MAP>
static __device__ __forceinline__ void st_tr(unsigned short* base, int r, int c, float4 a, float4 b){
    float aa[4] = {a.x, a.y, a.z, a.w}, bb[4] = {b.x, b.y, b.z, b.w};
#pragma unroll
    for (int e = 0; e < 4; ++e) {
        float x0 = MAP ? fmap(aa[e]) : aa[e];
        float x1 = MAP ? fmap(bb[e]) : bb[e];
        *(ushortx2*)(base + SWZ(c+e, r)) = ushortx2{ f2bf(x0), f2bf(x1) };
    }
}

// ---------------- kA: per-oct KV accumulation with CUMULATIVE per-chunk snapshots ----------------
// 512 threads (8 waves, dt-split) -> 16 waves/CU at grid 512.
__global__ __launch_bounds__(512) void kA(const float* __restrict__ kp, const float* __restrict__ vp,
                                          unsigned short* __restrict__ snap, float* __restrict__ ksnap)
{
    __shared__ __align__(16) unsigned short kft[2][DD*PAD]; // kf^T [d][s] (SWZ)
    __shared__ __align__(16) unsigned short vtt[2][DD*PAD]; // v^T  [m][s] (SWZ)
    const int blk = blockIdx.x;                 // bh*8 + oct
    const int bh = blk >> 3, oct = blk & 7, b = bh >> 4, h = bh & 15;
    const int t = threadIdx.x;
    const int w = t >> 6, lane = t & 63, quad = lane >> 4, lr = lane & 15;
    const int m0 = 16*(w & 3), dth = (w >> 2) << 1;   // wave owns m-tile m0, dt tiles {dth, dth+1}
    const int l0s = (t >> 4) * 2, col4 = (t & 15) << 2;   // 512 staging slots

    floatx4 acc[2];
    acc[0] = floatx4{0.f,0.f,0.f,0.f};
    acc[1] = floatx4{0.f,0.f,0.f,0.f};
    float ksa = 0.f;

    const int64_t gb0 = ((int64_t)(b*LL + oct*256)*HH + h)*DD;
    // prologue: stage sub-chunk 0
    {
        const float* gk = kp + gb0 + (int64_t)l0s*LSTR + col4;
        const float* gv = vp + gb0 + (int64_t)l0s*LSTR + col4;
        float4 ka = *(const float4*)gk, kb = *(const float4*)(gk + LSTR);
        float4 va = *(const float4*)gv, vb = *(const float4*)(gv + LSTR);
        st_tr<true >(kft[0], l0s, col4, ka, kb);
        st_tr<false>(vtt[0], l0s, col4, va, vb);
    }
    __syncthreads();

#pragma unroll 1
    for (int sc = 0; sc < 4; ++sc) {
        const int p = sc & 1;
        float4 ka, kb, va, vb;
        if (sc < 3) {
            const int64_t gb = gb0 + (int64_t)(sc+1)*DD*LSTR;
            const float* gk = kp + gb + (int64_t)l0s*LSTR + col4;
            const float* gv = vp + gb + (int64_t)l0s*LSTR + col4;
            ka = *(const float4*)gk; kb = *(const float4*)(gk + LSTR);
            va = *(const float4*)gv; vb = *(const float4*)(gv + LSTR);
        }
        // accumulate KV^T[m][d] over this sub-chunk (this wave's 2 dt tiles)
#pragma unroll
        for (int kk = 0; kk < 2; ++kk) {
            bf16x8 a = ldf(vtt[p] + SWZ(m0+lr, kk*32 + quad*8));
#pragma unroll
            for (int dtl = 0; dtl < 2; ++dtl) {
                bf16x8 bbf = ldf(kft[p] + SWZ((dth+dtl)*16+lr, kk*32 + quad*8));
                acc[dtl] = __builtin_amdgcn_mfma_f32_16x16x32_bf16(a, bbf, acc[dtl], 0, 0, 0);
            }
        }
        // snapshot: cumulative KV (bf16) for chunks 0..sc
        {
            unsigned short* so = snap + ((int64_t)blk*4 + sc)*4096;
#pragma unroll
            for (int dtl = 0; dtl < 2; ++dtl)
#pragma unroll
                for (int r = 0; r < 4; ++r)
                    so[(m0 + quad*4 + r)*DD + (dth+dtl)*16 + lr] = f2bf(acc[dtl][r]);
        }
        // cumulative K colsum snapshot
        if (t < DD) {
#pragma unroll
            for (int jj = 0; jj < 8; ++jj) {
                ushortx8 u = *(const ushortx8*)(kft[p] + SWZ(t, jj*8));
#pragma unroll
                for (int e = 0; e < 8; ++e) ksa += bf2f(u[e]);
            }
            ksnap[((int64_t)blk*4 + sc)*DD + t] = ksa;
        }
        if (sc < 3) {
            st_tr<true >(kft[p^1], l0s, col4, ka, kb);
            st_tr<false>(vtt[p^1], l0s, col4, va, vb);
        }
        __syncthreads();
    }
}

// ---------------- kB: cross-oct prefix of full-oct snapshots (fp32), fully parallel ----------------
// spre[blk] = fp32 [m][d] sum of full-oct KV for octs < oct;  kpre[blk] = fp32 [d] same for colsums
__global__ __launch_bounds__(256) void kB(const unsigned short* __restrict__ snap,
                                          const float* __restrict__ ksnap,
                                          float* __restrict__ spre, float* __restrict__ kpre)
{
    const int blk = blockIdx.x;                 // bh*8 + oct
    const int bh = blk >> 3, oct = blk & 7;
    const int t = threadIdx.x;
    const int m = t >> 2, d0 = (t & 3) << 4;
    const unsigned short* sb = snap + (((int64_t)bh*8)*4 + 3)*4096 + m*DD + d0;
    float acc[16];
#pragma unroll
    for (int e = 0; e < 16; ++e) acc[e] = 0.f;
#pragma unroll
    for (int half = 0; half < 2; ++half) {
        ushortx8 u[7];
#pragma unroll
        for (int op = 0; op < 7; ++op)
            if (op < oct) u[op] = *(const ushortx8*)(sb + (int64_t)op*4*4096 + half*8);
#pragma unroll
        for (int op = 0; op < 7; ++op)
            if (op < oct)
#pragma unroll
                for (int e = 0; e < 8; ++e) acc[half*8+e] += bf2f(u[op][e]);
    }
    float* so = spre + (int64_t)blk*4096 + m*DD + d0;
#pragma unroll
    for (int g = 0; g < 4; ++g)
        *(float4*)(so + 4*g) = float4{acc[4*g], acc[4*g+1], acc[4*g+2], acc[4*g+3]};
    if (t < DD) {
        float s = 0.f;
#pragma unroll
        for (int op = 0; op < 7; ++op)
            if (op < oct) s += ksnap[(((int64_t)bh*8 + op)*4 + 3)*DD + t];
        kpre[(int64_t)blk*DD + t] = s;
    }
}

// ---------------- kC: one block per 64-row chunk, flat prefix loads, 3 barriers ----------------
// LDS 30.2 KB -> 5 blocks/CU (launch_bounds(256,5): VGPR cap ~102)
__global__ __launch_bounds__(256, 5) void kC(const float* __restrict__ qp, const float* __restrict__ kp,
                                             const float* __restrict__ vp,
                                             const unsigned short* __restrict__ snap,
                                             const float* __restrict__ ksnap,
                                             const float* __restrict__ spre,
                                             const float* __restrict__ kpre,
                                             float* __restrict__ outp)
{
    __shared__ __align__(16) unsigned short qf [DD*PAD];  // [l][d]; becomes wave-private score scratch
    __shared__ __align__(16) unsigned short kfx[80*PAD];  // [s][d]; row64 = ksum prefix, 65-79 = 0
    __shared__ __align__(16) unsigned short vtt[DD*PAD];  // v^T [m][s] (SWZ); reused for S [m][d] (SWZ)
    __shared__ float zr[DD];
    const int orig = blockIdx.x;
    const int bid = ((orig & 7) << 8) | (orig >> 3);      // XCD swizzle: same-bh blocks share an XCD L2
    const int bh = bid >> 5, c = bid & 31, b = bh >> 4, h = bh & 15;
    const int o = c >> 2, j = c & 3;            // oct, chunk-within-oct
    const int t = threadIdx.x;
    const int64_t gbase = ((int64_t)(b*LL + c*DD)*HH + h)*DD;

    // ---- S prefix: flat loads (oct prefix fp32 + optional within-oct remainder bf16) ----
    const int sm = t >> 2, sd0 = (t & 3) << 4;  // thread owns S[sm][sd0..sd0+15]
    ushortx8 sw0, sw1;                          // bf16 S carried in 8 regs across barriers
    {
        const float* pp = spre + ((int64_t)(bh*8 + o))*4096 + sm*DD + sd0;
        float4 p0 = *(const float4*)(pp);
        float4 p1 = *(const float4*)(pp + 4);
        float4 p2 = *(const float4*)(pp + 8);
        float4 p3 = *(const float4*)(pp + 12);
        float sa[16] = {p0.x,p0.y,p0.z,p0.w, p1.x,p1.y,p1.z,p1.w,
                        p2.x,p2.y,p2.z,p2.w, p3.x,p3.y,p3.z,p3.w};
        if (j > 0) {
            const unsigned short* sp = snap + (((int64_t)(bh*8 + o))*4 + (j-1))*4096 + sm*DD + sd0;
            ushortx8 u0 = *(const ushortx8*)sp, u1 = *(const ushortx8*)(sp + 8);
#pragma unroll
            for (int e = 0; e < 8; ++e) { sa[e] += bf2f(u0[e]); sa[8+e] += bf2f(u1[e]); }
        }
#pragma unroll
        for (int e = 0; e < 8; ++e) { sw0[e] = f2bf(sa[e]); sw1[e] = f2bf(sa[8+e]); }
    }

    // ---- stage q,k,v for own 64 rows ----
#pragma unroll
    for (int i = 0; i < 2; ++i) {
        int flat = t + 256*i;
        int l0s = (flat >> 4) * 2, col = (flat & 15) << 2;
        const float* gq = qp + gbase + (int64_t)l0s*LSTR + col;
        const float* gk = kp + gbase + (int64_t)l0s*LSTR + col;
        const float* gv = vp + gbase + (int64_t)l0s*LSTR + col;
        float4 qa = *(const float4*)(gq), qb = *(const float4*)(gq + LSTR);
        float4 ka = *(const float4*)(gk), kb = *(const float4*)(gk + LSTR);
        float4 va = *(const float4*)(gv), vb = *(const float4*)(gv + LSTR);
        st_sd<true >(qf , l0s, col, qa, qb);
        st_sd<true >(kfx, l0s, col, ka, kb);
        st_tr<false>(vtt, l0s, col, va, vb);
    }
    if (t < 135) *(ushortx8*)(kfx + 65*PAD + t*8) = ushortx8{0,0,0,0,0,0,0,0};
    if (t < DD) {
        float s = kpre[((int64_t)(bh*8 + o))*DD + t];
        if (j > 0) s += ksnap[(((int64_t)(bh*8 + o))*4 + (j-1))*DD + t];
        kfx[64*PAD + t] = f2bf(s);
    }
    __syncthreads();   // barrier A

    const int w = t >> 6, lane = t & 63, quad = lane >> 4, lr = lane & 15;
    const int l0 = 16*w;
    // A-frags of qf (own rows only -> qf becomes wave-private scratch)
    bf16x8 aq[2];
    aq[0] = ldf(qf + (l0+lr)*PAD + quad*8);
    aq[1] = ldf(qf + (l0+lr)*PAD + 32 + quad*8);

    // ---- GEMM1: scores = qf * kf^T; tile 4 col0 = qf . Kprefix ----
    floatx4 sc5[5];
#pragma unroll
    for (int tt = 0; tt < 5; ++tt) sc5[tt] = floatx4{0.f,0.f,0.f,0.f};
#pragma unroll
    for (int kk = 0; kk < 2; ++kk)
#pragma unroll
        for (int tt = 0; tt < 5; ++tt) {
            bf16x8 bb = ldf(kfx + (tt*16+lr)*PAD + kk*32 + quad*8);
            sc5[tt] = __builtin_amdgcn_mfma_f32_16x16x32_bf16(aq[kk], bb, sc5[tt], 0, 0, 0);
        }

    // ---- causal mask, z row-sums, overlay masked scores onto own qf rows ----
    float zp[4] = {0.f,0.f,0.f,0.f};
#pragma unroll
    for (int tt = 0; tt < 4; ++tt)
#pragma unroll
        for (int r = 0; r < 4; ++r) {
            int row = l0 + quad*4 + r;
            int col = tt*16 + lr;
            float val = (col <= row) ? sc5[tt][r] : 0.f;
            zp[r] += val;
            qf[row*PAD + col] = f2bf(val);
        }
#pragma unroll
    for (int r = 0; r < 4; ++r) zp[r] += (lr == 0) ? sc5[4][r] : 0.f;
#pragma unroll
    for (int m = 1; m < 16; m <<= 1)
#pragma unroll
        for (int r = 0; r < 4; ++r) zp[r] += __shfl_xor(zp[r], m, 64);
    if (lr == 0)
#pragma unroll
        for (int r = 0; r < 4; ++r) zr[l0 + quad*4 + r] = 1.f / (zp[r] + EPSF);

    // ---- GEMM2a: out = Amask * v (vtt still holds v^T) ----
    floatx4 oa[4];
#pragma unroll
    for (int mt = 0; mt < 4; ++mt) oa[mt] = floatx4{0.f,0.f,0.f,0.f};
#pragma unroll
    for (int kk = 0; kk < 2; ++kk) {
        bf16x8 a2 = ldf(qf + (l0+lr)*PAD + kk*32 + quad*8);    // own rows (intra-wave RAW)
#pragma unroll
        for (int mt = 0; mt < 4; ++mt) {
            bf16x8 bv = ldf(vtt + SWZ(mt*16+lr, kk*32 + quad*8));
            oa[mt] = __builtin_amdgcn_mfma_f32_16x16x32_bf16(a2, bv, oa[mt], 0, 0, 0);
        }
    }
    __syncthreads();   // barrier B: all waves done reading v^T

    // ---- publish S into vtt's space ([m][d], SWZ) ----
    *(ushortx8*)(vtt + SWZ(sm, sd0))     = sw0;
    *(ushortx8*)(vtt + SWZ(sm, sd0 + 8)) = sw1;
    __syncthreads();   // barrier C: S visible

    // ---- GEMM2b: out += qf * S ----
#pragma unroll
    for (int kk = 0; kk < 2; ++kk)
#pragma unroll
        for (int mt = 0; mt < 4; ++mt) {
            bf16x8 bs = ldf(vtt + SWZ(mt*16+lr, kk*32 + quad*8));
            oa[mt] = __builtin_amdgcn_mfma_f32_16x16x32_bf16(aq[kk], bs, oa[mt], 0, 0, 0);
        }
#pragma unroll
    for (int r = 0; r < 4; ++r) {
        int row = l0 + quad*4 + r;
        float rz = zr[row];
#pragma unroll
        for (int mt = 0; mt < 4; ++mt)
            outp[gbase + (int64_t)row*LSTR + mt*16 + lr] = oa[mt][r] * rz;
    }
}

extern "C" void kernel_launch(void* const* d_in, const int* in_sizes, int n_in,
                              void* d_out, int out_size, void* d_ws, size_t ws_size,
                              hipStream_t stream) {
    const float* q = (const float*)d_in[0];
    const float* k = (const float*)d_in[1];
    const float* v = (const float*)d_in[2];
    float* out = (float*)d_out;
    char* ws = (char*)d_ws;
    unsigned short* snap = (unsigned short*)ws;                       // 512*4*4096 bf16 = 16 MiB
    float* ksnap = (float*)(ws + (size_t)512*4*4096*2);               // 512*4*64 fp32 = 512 KiB
    float* spre  = (float*)(ws + (size_t)512*4*4096*2 + 512*4*64*4);  // 512*4096 fp32 = 8 MiB
    float* kpre  = (float*)(ws + (size_t)512*4*4096*2 + 512*4*64*4 + (size_t)512*4096*4); // 128 KiB
    kA<<<512,  512, 0, stream>>>(k, v, snap, ksnap);
    kB<<<512,  256, 0, stream>>>(snap, ksnap, spre, kpre);
    kC<<<2048, 256, 0, stream>>>(q, k, v, snap, ksnap, spre, kpre, out);
}